// Round 2
// baseline (17454.346 us; speedup 1.0000x reference)
//
#include <hip/hip_runtime.h>
#include <math.h>

#define T_SEQ 2048
#define DD 1024
#define HH 4096
#define NLAYER 8
#define VV 50257
#define LN_EPS 1e-5f

// ---------------- LayerNorm (one block per row, D=1024, 256 thr x float4) ----
// If tok != nullptr, row is gathered from `in` at tok[blockIdx.x] (embedding).
__global__ __launch_bounds__(256) void ln_kernel(
    const float* __restrict__ in, const float* __restrict__ w,
    const float* __restrict__ b, float* __restrict__ out,
    const int* __restrict__ tok)
{
    int t = blockIdx.x;
    int tid = threadIdx.x;
    long rowi = tok ? (long)tok[t] : (long)t;
    const float4* rp = (const float4*)(in + rowi * DD);
    float4 xv = rp[tid];
    float s = xv.x + xv.y + xv.z + xv.w;
    float q = xv.x * xv.x + xv.y * xv.y + xv.z * xv.z + xv.w * xv.w;
    #pragma unroll
    for (int off = 32; off > 0; off >>= 1) {
        s += __shfl_down(s, off);
        q += __shfl_down(q, off);
    }
    __shared__ float ss[4], sq[4];
    __shared__ float mu_s, inv_s;
    int wave = tid >> 6, lane = tid & 63;
    if (lane == 0) { ss[wave] = s; sq[wave] = q; }
    __syncthreads();
    if (tid == 0) {
        float ts = ss[0] + ss[1] + ss[2] + ss[3];
        float tq = sq[0] + sq[1] + sq[2] + sq[3];
        float mu = ts * (1.0f / DD);
        float var = tq * (1.0f / DD) - mu * mu;   // population var (jnp.var)
        mu_s = mu;
        inv_s = rsqrtf(var + LN_EPS);
    }
    __syncthreads();
    float mu = mu_s, inv = inv_s;
    float4 wv = ((const float4*)w)[tid];
    float4 bv = ((const float4*)b)[tid];
    float4 o;
    o.x = (xv.x - mu) * inv * wv.x + bv.x;
    o.y = (xv.y - mu) * inv * wv.y + bv.y;
    o.z = (xv.z - mu) * inv * wv.z + bv.z;
    o.w = (xv.w - mu) * inv * wv.w + bv.w;
    ((float4*)(out + (size_t)t * DD))[tid] = o;
}

// ---------------- token-shift mix: o_j = x*m_j + shift(x)*(1-m_j) -----------
__global__ __launch_bounds__(256) void mix_kernel(
    const float* __restrict__ x,
    const float* __restrict__ m0, const float* __restrict__ m1,
    const float* __restrict__ m2,
    float* __restrict__ o0, float* __restrict__ o1, float* __restrict__ o2)
{
    int idx = blockIdx.x * 256 + threadIdx.x;
    int d = idx & (DD - 1);
    float xc = x[idx];
    float xp = (idx >= DD) ? x[idx - DD] : 0.0f;  // t=0 row gets zeros
    float m;
    m = m0[d]; o0[idx] = xc * m + xp * (1.0f - m);
    m = m1[d]; o1[idx] = xc * m + xp * (1.0f - m);
    if (m2) { m = m2[d]; o2[idx] = xc * m + xp * (1.0f - m); }
}

// ---------------- WKV recurrence: one thread per channel, fused r.*y --------
__global__ __launch_bounds__(256) void wkv_kernel(
    const float* __restrict__ k, const float* __restrict__ v,
    const float* __restrict__ r,
    const float* __restrict__ td, const float* __restrict__ tf,
    float* __restrict__ y)
{
    int c = blockIdx.x * 256 + threadIdx.x;   // 1024 threads total
    float w = -expf(td[c]);
    float u = tf[c];
    float aa = 0.f, bb = 0.f, pp = -1e30f;
    for (int t = 0; t < T_SEQ; ++t) {
        int idx = t * DD + c;
        float kt = k[idx], vt = v[idx];
        float ww = u + kt;
        float qq = fmaxf(pp, ww);
        float e1 = expf(pp - qq), e2 = expf(ww - qq);
        y[idx] = r[idx] * ((e1 * aa + e2 * vt) / (e1 * bb + e2));
        float ww2 = pp + w;
        float qq2 = fmaxf(ww2, kt);
        e1 = expf(ww2 - qq2); e2 = expf(kt - qq2);
        aa = e1 * aa + e2 * vt;
        bb = e1 * bb + e2;
        pp = qq2;
    }
}

// ---------------- fp32 tiled GEMM: 128 x BN_ x 16, 8 x TN_ per thread -------
// mode 0: store   1: sigmoid   2: relu^2   3: C += AB   4: C += mul .* AB
#define BK 16

__device__ __forceinline__ float ep_apply(float val, float cv, float mv, int mode)
{
    if (mode == 1) return 1.0f / (1.0f + expf(-val));
    if (mode == 2) { val = fmaxf(val, 0.0f); return val * val; }
    if (mode == 3) return cv + val;
    if (mode == 4) return cv + mv * val;
    return val;
}

template<int BN_, int TN_>
__device__ __forceinline__ void gemm_body(
    const float* __restrict__ A, const float* __restrict__ B,
    float* __restrict__ C, int M, int N, int K, int mode,
    const float* __restrict__ mul, int bx, int by)
{
    constexpr int BM_ = 128;
    constexpr int TM_ = 8;
    __shared__ float As[BK][BM_];   // transposed A tile
    __shared__ float Bs[BK][BN_];
    const int tid = threadIdx.x;
    const int tx = tid & 15;        // 16 thread-cols
    const int ty = tid >> 4;        // 16 thread-rows
    const int bm = by * BM_;
    const int bn = bx * BN_;
    const int arow = tid >> 1;            // 0..127
    const int acol = (tid & 1) << 3;      // 0 or 8
    const bool nvec = ((N & 3) == 0);     // head (N odd): rows only 4B-aligned
    const bool inb  = (bn + BN_ <= N);    // tile fully inside N
    float acc[TM_][TN_] = {};

    for (int k0 = 0; k0 < K; k0 += BK) {
        // stage A: 2x float4 along K, transpose into As
        const float* ap = A + (size_t)(bm + arow) * K + k0 + acol;
        float4 av0 = *(const float4*)(ap);
        float4 av1 = *(const float4*)(ap + 4);
        As[acol + 0][arow] = av0.x;
        As[acol + 1][arow] = av0.y;
        As[acol + 2][arow] = av0.z;
        As[acol + 3][arow] = av0.w;
        As[acol + 4][arow] = av1.x;
        As[acol + 5][arow] = av1.y;
        As[acol + 6][arow] = av1.z;
        As[acol + 7][arow] = av1.w;
        // stage B
        constexpr int NB4 = BN_ / 4;
        #pragma unroll
        for (int i = tid; i < BK * NB4; i += 256) {
            int brw = i / NB4;
            int bcl = (i - brw * NB4) << 2;
            const float* bp = B + (size_t)(k0 + brw) * N + bn + bcl;
            float4 b4;
            if (nvec && inb) {
                b4 = *(const float4*)bp;
            } else if (inb) {                 // interior head tile: unguarded scalar
                b4.x = bp[0]; b4.y = bp[1]; b4.z = bp[2]; b4.w = bp[3];
            } else {                          // ragged tail tile
                int nr = N - (bn + bcl);
                b4.x = (nr > 0) ? bp[0] : 0.0f;
                b4.y = (nr > 1) ? bp[1] : 0.0f;
                b4.z = (nr > 2) ? bp[2] : 0.0f;
                b4.w = (nr > 3) ? bp[3] : 0.0f;
            }
            *(float4*)(&Bs[brw][bcl]) = b4;
        }
        __syncthreads();
        #pragma unroll
        for (int kk = 0; kk < BK; ++kk) {
            float a[TM_], b[TN_];
            #pragma unroll
            for (int i4 = 0; i4 < TM_; i4 += 4)
                *(float4*)(&a[i4]) = *(const float4*)(&As[kk][ty * TM_ + i4]);
            #pragma unroll
            for (int j4 = 0; j4 < TN_; j4 += 4)
                *(float4*)(&b[j4]) = *(const float4*)(&Bs[kk][tx * TN_ + j4]);
            #pragma unroll
            for (int i = 0; i < TM_; ++i)
                #pragma unroll
                for (int j = 0; j < TN_; ++j)
                    acc[i][j] = fmaf(a[i], b[j], acc[i][j]);
        }
        __syncthreads();
    }

    // epilogue (M always a multiple of 128 here)
    #pragma unroll
    for (int i = 0; i < TM_; ++i) {
        int m = bm + ty * TM_ + i;
        if (nvec && inb) {
            #pragma unroll
            for (int j4 = 0; j4 < TN_; j4 += 4) {
                int n = bn + tx * TN_ + j4;
                size_t idx = (size_t)m * N + n;
                float4 cv4 = {0.f, 0.f, 0.f, 0.f};
                float4 mv4 = {0.f, 0.f, 0.f, 0.f};
                if (mode >= 3) cv4 = *(const float4*)(C + idx);
                if (mode == 4) mv4 = *(const float4*)(mul + idx);
                float4 o4;
                o4.x = ep_apply(acc[i][j4 + 0], cv4.x, mv4.x, mode);
                o4.y = ep_apply(acc[i][j4 + 1], cv4.y, mv4.y, mode);
                o4.z = ep_apply(acc[i][j4 + 2], cv4.z, mv4.z, mode);
                o4.w = ep_apply(acc[i][j4 + 3], cv4.w, mv4.w, mode);
                *(float4*)(C + idx) = o4;
            }
        } else {
            #pragma unroll
            for (int j = 0; j < TN_; ++j) {
                int n = bn + tx * TN_ + j;
                if (n < N) {
                    size_t idx = (size_t)m * N + n;
                    float cv = 0.f, mv = 0.f;
                    if (mode >= 3) cv = C[idx];
                    if (mode == 4) mv = mul[idx];
                    C[idx] = ep_apply(acc[i][j], cv, mv, mode);
                }
            }
        }
    }
}

template<int BN_, int TN_>
__global__ __launch_bounds__(256, 2) void gemm_kernel(
    const float* __restrict__ A, const float* __restrict__ B,
    float* __restrict__ C, int M, int N, int K, int mode,
    const float* __restrict__ mul)
{
    gemm_body<BN_, TN_>(A, B, C, M, N, K, mode, mul, blockIdx.x, blockIdx.y);
}

// batched k/v/r GEMMs (independent; z selects). N=K=1024, mode: z==2 -> sigmoid
__global__ __launch_bounds__(256, 2) void gemm_krv_kernel(
    const float* __restrict__ A0, const float* __restrict__ A1,
    const float* __restrict__ A2,
    const float* __restrict__ B0, const float* __restrict__ B1,
    const float* __restrict__ B2,
    float* __restrict__ C0, float* __restrict__ C1, float* __restrict__ C2,
    int M, int N, int K)
{
    int z = blockIdx.z;
    const float* A = (z == 0) ? A0 : (z == 1) ? A1 : A2;
    const float* B = (z == 0) ? B0 : (z == 1) ? B1 : B2;
    float*       C = (z == 0) ? C0 : (z == 1) ? C1 : C2;
    int mode = (z == 2) ? 1 : 0;
    gemm_body<64, 4>(A, B, C, M, N, K, mode, nullptr, blockIdx.x, blockIdx.y);
}

// batched channel-mix pair: z=0 -> relu^2 (N0=H), z=1 -> sigmoid (N1=D)
__global__ __launch_bounds__(256, 2) void gemm_cm_kernel(
    const float* __restrict__ A0, const float* __restrict__ B0,
    float* __restrict__ C0, int N0, int mode0,
    const float* __restrict__ A1, const float* __restrict__ B1,
    float* __restrict__ C1, int N1, int mode1,
    int M, int K)
{
    int z = blockIdx.z;
    const float* A = z ? A1 : A0;
    const float* B = z ? B1 : B0;
    float*       C = z ? C1 : C0;
    int N    = z ? N1 : N0;
    int mode = z ? mode1 : mode0;
    if ((int)blockIdx.x * 64 >= N) return;   // uniform early-exit, no barriers hit
    gemm_body<64, 4>(A, B, C, M, N, K, mode, nullptr, blockIdx.x, blockIdx.y);
}

extern "C" void kernel_launch(void* const* d_in, const int* in_sizes, int n_in,
                              void* d_out, int out_size, void* d_ws, size_t ws_size,
                              hipStream_t stream)
{
    const int*   tokens    = (const int*)  d_in[0];
    const float* emb       = (const float*)d_in[1];
    const float* tm_decay  = (const float*)d_in[2];
    const float* tm_first  = (const float*)d_in[3];
    const float* tm_mix_k  = (const float*)d_in[4];
    const float* tm_mix_v  = (const float*)d_in[5];
    const float* tm_mix_r  = (const float*)d_in[6];
    const float* tm_Wk     = (const float*)d_in[7];
    const float* tm_Wv     = (const float*)d_in[8];
    const float* tm_Wr     = (const float*)d_in[9];
    const float* tm_Wo     = (const float*)d_in[10];
    const float* cm_mix_k  = (const float*)d_in[11];
    const float* cm_mix_r  = (const float*)d_in[12];
    const float* cm_Wk     = (const float*)d_in[13];
    const float* cm_Wv     = (const float*)d_in[14];
    const float* cm_Wr     = (const float*)d_in[15];
    const float* ln0_w     = (const float*)d_in[16];
    const float* ln0_b     = (const float*)d_in[17];
    const float* ln1_w     = (const float*)d_in[18];
    const float* ln1_b     = (const float*)d_in[19];
    const float* ln2_w     = (const float*)d_in[20];
    const float* ln2_b     = (const float*)d_in[21];
    const float* ln_out_w  = (const float*)d_in[22];
    const float* ln_out_b  = (const float*)d_in[23];
    const float* head_W    = (const float*)d_in[24];
    float* out = (float*)d_out;
    float* ws  = (float*)d_ws;

    const size_t TD = (size_t)T_SEQ * DD;
    // workspace layout: 8 x [T,D] buffers + 1 x [T,H] buffer = 96 MB
    if (ws_size < (8 * TD + (size_t)T_SEQ * HH) * sizeof(float)) return;
    float* x  = ws;            // residual stream
    float* xn = ws + 1 * TD;   // LN2 / LN_out output
    float* a0 = ws + 2 * TD;   // mix-k input, later cm mix-k
    float* a1 = ws + 3 * TD;   // mix-v input, later ry, later cm mix-r
    float* a2 = ws + 4 * TD;   // mix-r input
    float* bk = ws + 5 * TD;   // k
    float* bv = ws + 6 * TD;   // v
    float* br = ws + 7 * TD;   // r, later rr
    float* kk = ws + 8 * TD;   // [T,H]

    const int EW_GRID = (int)(TD / 256);   // 8192 blocks for [T,D] elementwise
    const dim3 gD(DD / 64, T_SEQ / 128);           // (16,16) 256 blocks
    const dim3 gKRV(DD / 64, T_SEQ / 128, 3);      // 768 blocks
    const dim3 gCM(HH / 64, T_SEQ / 128, 2);       // z=0 uses 64 x-blocks, z=1 uses 16
    const dim3 gHEAD((VV + 127) / 128, T_SEQ / 128);

    // x = LN0(emb[tokens])
    ln_kernel<<<T_SEQ, 256, 0, stream>>>(emb, ln0_w, ln0_b, x, tokens);

    for (int l = 0; l < NLAYER; ++l) {
        const size_t oD  = (size_t)l * DD;
        const size_t oDD = (size_t)l * DD * DD;
        const size_t oDH = (size_t)l * DD * HH;

        // x = LN1(x)  (faithful: LN1 output becomes the residual stream)
        ln_kernel<<<T_SEQ, 256, 0, stream>>>(x, ln1_w + oD, ln1_b + oD, x, nullptr);
        // token-shift mixes for k/v/r
        mix_kernel<<<EW_GRID, 256, 0, stream>>>(x, tm_mix_k + oD, tm_mix_v + oD,
                                                tm_mix_r + oD, a0, a1, a2);
        // k/v/r GEMMs batched in one launch (r gets sigmoid epilogue)
        gemm_krv_kernel<<<gKRV, 256, 0, stream>>>(a0, a1, a2,
                                                  tm_Wk + oDD, tm_Wv + oDD, tm_Wr + oDD,
                                                  bk, bv, br, T_SEQ, DD, DD);
        // a1 = r .* wkv(-exp(td), tf, k, v)
        wkv_kernel<<<DD / 256, 256, 0, stream>>>(bk, bv, br, tm_decay + oD,
                                                 tm_first + oD, a1);
        // x += (r.*y) @ Wo
        gemm_kernel<64, 4><<<gD, 256, 0, stream>>>(a1, tm_Wo + oDD, x,
                                                   T_SEQ, DD, DD, 3, nullptr);

        // xn = LN2(x)
        ln_kernel<<<T_SEQ, 256, 0, stream>>>(x, ln2_w + oD, ln2_b + oD, xn, nullptr);
        // channel-mix token-shift mixes
        mix_kernel<<<EW_GRID, 256, 0, stream>>>(xn, cm_mix_k + oD, cm_mix_r + oD,
                                                nullptr, a0, a1, nullptr);
        // kk = relu(a0 @ CWk)^2 [T,H]  and  rr = sigmoid(a1 @ CWr) [T,D], one launch
        gemm_cm_kernel<<<gCM, 256, 0, stream>>>(a0, cm_Wk + oDH, kk, HH, 2,
                                                a1, cm_Wr + oDD, br, DD, 1,
                                                T_SEQ, DD);
        // x += rr .* (kk @ CWv)
        gemm_kernel<64, 4><<<gD, 256, 0, stream>>>(kk, cm_Wv + (size_t)l * HH * DD, x,
                                                   T_SEQ, DD, HH, 4, br);
    }

    // out = LN_out(x) @ head_W
    ln_kernel<<<T_SEQ, 256, 0, stream>>>(x, ln_out_w, ln_out_b, xn, nullptr);
    gemm_kernel<128, 8><<<gHEAD, 256, 0, stream>>>(xn, head_W, out,
                                                   T_SEQ, VV, DD, 0, nullptr);
}